// Round 8
// baseline (656.123 us; speedup 1.0000x reference)
//
#include <hip/hip_runtime.h>
#include <hip/hip_bf16.h>
#include <stdint.h>

// RoPEDemoAttention on MI355X (gfx950)
// B=4, S=4096, D=256. fp32 in/out.
// K0: split fp32 -> bf16 hi/lo + RoPE cos/sin table.
// K1: Q/K/V projections via 3-pass split-bf16 MFMA + RoPE.
// K2 (R8): 512 blocks x 32 q-rows -> 2 blocks/CU (4 waves/SIMD).
//   Only K-hi staged in LDS (dbuf 2x32K); K-lo read direct (L2-hot).
//   Same 1-barrier pipelined skeleton as R3/R7:
//     stage(kt+1) -> ecopy+PV(kt-1) -> scores(kt) -> exp -> barrier
//   then rowsums, normalized out, 5-phase in-place e->weights sweep.
//   XCD-pinning swizzle: swz = (bid&7)*64 + ((bid>>3)&31)*2 + (bid>>8)
//   (bijective; each XCD hosts 64 contiguous q-subtiles of ONE batch;
//   co-resident pair (bid, bid+256) = adjacent q-subtiles).

#define B_ 4
#define S_ 4096
#define D_ 256
#define NQ 4194304   // B_*S_*D_
#define NW 65536     // D_*D_
#define NTAB 524288  // S_*128 table entries (cos,sin pairs)

typedef __attribute__((ext_vector_type(4))) float f32x4;
typedef __attribute__((ext_vector_type(8))) short short8;
typedef __attribute__((ext_vector_type(4))) short short4v;
typedef __attribute__((ext_vector_type(4))) unsigned uint32x4;

__device__ __forceinline__ short f2bf(float f) {
  unsigned u = __builtin_bit_cast(unsigned, f);
  u += 0x7fffu + ((u >> 16) & 1u);   // RNE
  return (short)(u >> 16);
}
__device__ __forceinline__ float bf2f(short h) {
  unsigned u = ((unsigned)(unsigned short)h) << 16;
  return __builtin_bit_cast(float, u);
}

__device__ __forceinline__ void gload16(const void* g, void* l) {
  __builtin_amdgcn_global_load_lds(
      (const __attribute__((address_space(1))) unsigned*)g,
      (__attribute__((address_space(3))) unsigned*)l, 16, 0, 0);
}

// ------------------------------------------------ K0: split + RoPE table
__global__ __launch_bounds__(256) void k0_split(
    const float* __restrict__ x, const float* __restrict__ wq,
    const float* __restrict__ wk, const float* __restrict__ wv,
    short* __restrict__ xh, short* __restrict__ xl,
    short* __restrict__ wh, short* __restrict__ wl,
    float* __restrict__ ctab) {
  int idx = blockIdx.x * 256 + threadIdx.x;  // grid = NQ + 3*NW + NTAB
  if (idx < NQ) {
    float v = x[idx];
    short hi = f2bf(v);
    xh[idx] = hi;
    xl[idx] = f2bf(v - bf2f(hi));
  } else if (idx < NQ + 3 * NW) {
    int r = idx - NQ;
    int m = r >> 16;
    int e = r & (NW - 1);
    const float* w = (m == 0) ? wq : (m == 1) ? wk : wv;
    float v = w[e];
    short hi = f2bf(v);
    wh[r] = hi;
    wl[r] = f2bf(v - bf2f(hi));
  } else {
    int t = idx - NQ - 3 * NW;          // t < NTAB
    int s = t >> 7, j = t & 127;
    float invf = __expf(-0.07195578415606394f * (float)j); // 10000^(-j/128)
    float sn, cs;
    sincosf((float)s * invf, &sn, &cs);
    ctab[2 * t] = cs;
    ctab[2 * t + 1] = sn;
  }
}

// ------------------------------------------------------- K1: proj + RoPE
__global__ __launch_bounds__(256) void k1_proj(
    const short* __restrict__ xh, const short* __restrict__ xl,
    const short* __restrict__ wh, const short* __restrict__ wl,
    const float* __restrict__ ctab,
    short* __restrict__ qh, short* __restrict__ ql,
    short* __restrict__ kh, short* __restrict__ kl,
    short* __restrict__ vt) {
  const int m = blockIdx.y;                 // 0=q 1=k 2=v
  const int b = blockIdx.x >> 6;
  const int sbase = (blockIdx.x & 63) << 6; // 64-row tile
  const int tid = threadIdx.x;
  const int w = tid >> 6;
  const int lane = tid & 63;
  const int lr = lane & 15;
  const int g = lane >> 4;

  const int srow = sbase + w * 16 + lr;     // A-frag row
  const short* xhp = xh + ((size_t)(b * S_ + srow)) * D_;
  const short* xlp = xl + ((size_t)(b * S_ + srow)) * D_;
  const short* whm = wh + m * NW;
  const short* wlm = wl + m * NW;

  f32x4 acc[16];
#pragma unroll
  for (int i = 0; i < 16; ++i) acc[i] = (f32x4)0.f;

#pragma unroll
  for (int dc = 0; dc < 8; ++dc) {
    const int d = dc * 32 + g * 8;
    short8 ah = *(const short8*)(xhp + d);
    short8 al = *(const short8*)(xlp + d);
#pragma unroll
    for (int ct = 0; ct < 16; ++ct) {
      const int e = ct * 16 + lr;
      short8 bh = *(const short8*)(whm + e * D_ + d);
      short8 bl = *(const short8*)(wlm + e * D_ + d);
      acc[ct] = __builtin_amdgcn_mfma_f32_16x16x32_bf16(ah, bh, acc[ct], 0, 0, 0);
      acc[ct] = __builtin_amdgcn_mfma_f32_16x16x32_bf16(ah, bl, acc[ct], 0, 0, 0);
      acc[ct] = __builtin_amdgcn_mfma_f32_16x16x32_bf16(al, bh, acc[ct], 0, 0, 0);
    }
  }

  const int s0 = sbase + w * 16 + g * 4;    // C/D row base
  if (m == 2) {
#pragma unroll
    for (int ct = 0; ct < 16; ++ct) {
      const int e = ct * 16 + lr;
      short4v pk;
#pragma unroll
      for (int r = 0; r < 4; ++r) pk[r] = f2bf(acc[ct][r]);
      *(short4v*)(vt + ((size_t)(b * D_ + e)) * S_ + s0) = pk;
    }
  } else {
    short* oh = (m == 0) ? qh : kh;
    short* ol = (m == 0) ? ql : kl;
#pragma unroll
    for (int ct = 0; ct < 16; ++ct) {
      const int e = ct * 16 + lr;
      const float sgn = (e & 1) ? 1.0f : -1.0f;  // rotate_half sign
#pragma unroll
      for (int r = 0; r < 4; ++r) {
        float v = acc[ct][r];
        float p = __shfl_xor(v, 1, 64);          // partner e^1, same s
        const float2 cs2 = *(const float2*)(ctab + ((size_t)((s0 + r) << 7) + (e & 127)) * 2);
        float q2 = v * cs2.x + sgn * p * cs2.y;
        short hi = f2bf(q2);
        size_t off = ((size_t)(b * S_ + s0 + r)) * D_ + e;
        oh[off] = hi;
        ol[off] = f2bf(q2 - bf2f(hi));
      }
    }
  }
}

// ------------- K2 fused: 32-q blocks, 2 blocks/CU, pipelined
__global__ __launch_bounds__(512, 2) void k2_fused(
    const short* __restrict__ qh, const short* __restrict__ ql,
    const short* __restrict__ kh, const short* __restrict__ kl,
    const short* __restrict__ vt,
    float* __restrict__ wts, float* __restrict__ out) {
  __shared__ __align__(16) char kbuf[65536];    // [2] K-hi tile [64][256]bf16
  __shared__ __align__(16) char etile[2][4096]; // e bf16 [32][64], swizzled
  __shared__ float part[4][32];
  __shared__ float lsum_l[32];

  const int bid = blockIdx.x;        // 512 blocks
  // XCD-pinning, co-resident-adjacent bijective swizzle
  const int swz = (bid & 7) * 64 + ((bid >> 3) & 31) * 2 + (bid >> 8);
  const int b = swz >> 7;            // batch
  const int qbase = (swz & 127) << 5;
  const int tid = threadIdx.x;
  const int w = tid >> 6;            // 8 waves
  const int lane = tid & 63;
  const int lr = lane & 15;
  const int g = lane >> 4;
  const int qg = w & 1;              // scores: which 16 q-rows
  const int kg = w >> 1;             // scores: which 16 keys of 64-key tile

  // Q hi/lo fragments (B-operand): 16 q-rows/wave -> 64 VGPR, resident
  short8 qfh[8], qfl[8];
  {
    const int qrow = qbase + qg * 16 + lr;
    const short* ph = qh + ((size_t)(b * S_ + qrow)) * D_;
    const short* pl = ql + ((size_t)(b * S_ + qrow)) * D_;
#pragma unroll
    for (int dc = 0; dc < 8; ++dc) {
      qfh[dc] = *(const short8*)(ph + dc * 32 + g * 8);
      qfl[dc] = *(const short8*)(pl + dc * 32 + g * 8);
    }
  }

  f32x4 acc = (f32x4)0.f;            // 16q x 16k per wave
  f32x4 accv[2][2];                  // PV: 32q x 32d per wave
#pragma unroll
  for (int qs = 0; qs < 2; ++qs)
#pragma unroll
    for (int dt = 0; dt < 2; ++dt) accv[qs][dt] = (f32x4)0.f;
  float rs = 0.f;

  const char* khb = (const char*)(kh + (size_t)b * S_ * D_);
  const char* klb = (const char*)(kl + (size_t)b * S_ * D_);
  const short* vtb = vt + (size_t)b * D_ * S_;
  const int swx = (lane & 7) << 4;   // K-LDS swizzle: (key&7)<<4

  // block's weights region (512 KiB); e-bf16 scratch in its top half
  char* WB = (char*)(wts + ((size_t)(b * S_ + qbase)) * S_);
  char* EB = WB + 262144;

  // prologue: stage K-hi tile 0 into kbuf[0]
#pragma unroll
  for (int i = 0; i < 4; ++i) {
    const int p = i * 8192 + tid * 16;
    const int xo = p ^ (((p >> 9) & 7) << 4);
    gload16(khb + xo, kbuf + p);
  }
  __syncthreads();

  for (int kt = 0; kt < 64; ++kt) {
    const int cur = kt & 1;
    const char* kb = kbuf + cur * 32768;

    // 1. stage next K-hi tile into the other buffer
    if (kt < 63) {
      const char* sh = khb + (size_t)(kt + 1) * 32768;
      char* kn = kbuf + (cur ^ 1) * 32768;
#pragma unroll
      for (int i = 0; i < 4; ++i) {
        const int p = i * 8192 + tid * 16;
        const int xo = p ^ (((p >> 9) & 7) << 4);
        gload16(sh + xo, kn + p);
      }
    }

    // 2. e-copy + PV of the PREVIOUS tile (etile[cur^1])
    if (kt > 0) {
      const char* et = etile[cur ^ 1];
      {
        const int p = tid * 8;             // 512 thr * 8B = 4 KB
        const int row = p >> 7, cb = p & 127;
        uint2 v = *(const uint2*)(et + (p ^ ((row & 7) << 4)));
        *(uint2*)(EB + (size_t)row * 8192 + (kt - 1) * 128 + cb) = v;
      }
      __builtin_amdgcn_s_setprio(1);
#pragma unroll
      for (int kk = 0; kk < 2; ++kk) {
        short8 ea0, ea1;
        {
          const int row = lr;
          ea0 = *(const short8*)(et + ((row * 128 + kk * 64 + g * 16) ^ ((row & 7) << 4)));
        }
        {
          const int row = 16 + lr;
          ea1 = *(const short8*)(et + ((row * 128 + kk * 64 + g * 16) ^ ((row & 7) << 4)));
        }
#pragma unroll
        for (int dt = 0; dt < 2; ++dt) {
          const int d = w * 32 + dt * 16 + lr;
          short8 vb = *(const short8*)(vtb + (size_t)d * S_ + (kt - 1) * 64 + kk * 32 + g * 8);
          accv[0][dt] = __builtin_amdgcn_mfma_f32_16x16x32_bf16(ea0, vb, accv[0][dt], 0, 0, 0);
          accv[1][dt] = __builtin_amdgcn_mfma_f32_16x16x32_bf16(ea1, vb, accv[1][dt], 0, 0, 0);
        }
      }
      __builtin_amdgcn_s_setprio(0);
    }

    // 3. scores: 3-pass split bf16 (K-hi from LDS, K-lo direct from global)
    __builtin_amdgcn_s_setprio(1);
#pragma unroll
    for (int dc = 0; dc < 8; ++dc) {
      const int row = kg * 16 + lr;
      const int x = (row * 512 + dc * 64 + g * 16) ^ swx;
      short8 afh = *(const short8*)(kb + x);
      short8 afl = *(const short8*)(klb + (size_t)(kt * 64 + row) * 512 + dc * 64 + g * 16);
      acc = __builtin_amdgcn_mfma_f32_16x16x32_bf16(afh, qfh[dc], acc, 0, 0, 0);
      acc = __builtin_amdgcn_mfma_f32_16x16x32_bf16(afh, qfl[dc], acc, 0, 0, 0);
      acc = __builtin_amdgcn_mfma_f32_16x16x32_bf16(afl, qfh[dc], acc, 0, 0, 0);
    }
    __builtin_amdgcn_s_setprio(0);

    // 4. e = exp(s/16) -> etile[cur] (bf16, swizzled) + rowsum
    {
      f32x4 e;
#pragma unroll
      for (int r = 0; r < 4; ++r) e[r] = __expf(acc[r] * 0.0625f);
      rs += e[0] + e[1] + e[2] + e[3];
      unsigned lo = (unsigned)(unsigned short)f2bf(e[0]) |
                    ((unsigned)(unsigned short)f2bf(e[1]) << 16);
      unsigned hi2 = (unsigned)(unsigned short)f2bf(e[2]) |
                     ((unsigned)(unsigned short)f2bf(e[3]) << 16);
      const int row = qg * 16 + lr;
      const int colb = (kg * 16 + g * 4) * 2;
      const int ad = (row * 128 + colb) ^ ((row & 7) << 4);
      *(uint2*)(etile[cur] + ad) = make_uint2(lo, hi2);
      acc = (f32x4)0.f;
    }
    __syncthreads();   // ONE barrier per tile
  }

  // ---- tail: e-copy + PV of tile 63 (etile[1])
  {
    const char* et = etile[1];
    {
      const int p = tid * 8;
      const int row = p >> 7, cb = p & 127;
      uint2 v = *(const uint2*)(et + (p ^ ((row & 7) << 4)));
      *(uint2*)(EB + (size_t)row * 8192 + 63 * 128 + cb) = v;
    }
#pragma unroll
    for (int kk = 0; kk < 2; ++kk) {
      short8 ea0, ea1;
      {
        const int row = lr;
        ea0 = *(const short8*)(et + ((row * 128 + kk * 64 + g * 16) ^ ((row & 7) << 4)));
      }
      {
        const int row = 16 + lr;
        ea1 = *(const short8*)(et + ((row * 128 + kk * 64 + g * 16) ^ ((row & 7) << 4)));
      }
#pragma unroll
      for (int dt = 0; dt < 2; ++dt) {
        const int d = w * 32 + dt * 16 + lr;
        short8 vb = *(const short8*)(vtb + (size_t)d * S_ + 63 * 64 + kk * 32 + g * 8);
        accv[0][dt] = __builtin_amdgcn_mfma_f32_16x16x32_bf16(ea0, vb, accv[0][dt], 0, 0, 0);
        accv[1][dt] = __builtin_amdgcn_mfma_f32_16x16x32_bf16(ea1, vb, accv[1][dt], 0, 0, 0);
      }
    }
  }

  // ---- rowsums -> lsum_l
  rs += __shfl_xor(rs, 16, 64);
  rs += __shfl_xor(rs, 32, 64);
  if (lane < 16) part[kg][qg * 16 + lane] = rs;
  __syncthreads();
  if (tid < 32)
    lsum_l[tid] = part[0][tid] + part[1][tid] + part[2][tid] + part[3][tid];
  __syncthreads();

  // ---- copy e rows 30,31 into LDS (their EB copies overwritten in P5)
#pragma unroll
  for (int i = 0; i < 2; ++i) {
    const int p = i * 8192 + tid * 16;
    *(uint32x4*)(kbuf + p) = *(const uint32x4*)(EB + (size_t)30 * 8192 + p);
  }

  // ---- normalized output write
  {
    float* ob = out + (size_t)b * S_ * D_;
    float rv[2][4];
#pragma unroll
    for (int qs = 0; qs < 2; ++qs)
#pragma unroll
      for (int r = 0; r < 4; ++r)
        rv[qs][r] = 1.0f / lsum_l[qs * 16 + g * 4 + r];
#pragma unroll
    for (int qs = 0; qs < 2; ++qs)
#pragma unroll
      for (int dt = 0; dt < 2; ++dt)
#pragma unroll
        for (int r = 0; r < 4; ++r) {
          const int q = qbase + qs * 16 + g * 4 + r;
          ob[(size_t)q * D_ + w * 32 + dt * 16 + lr] = accv[qs][dt][r] * rv[qs][r];
        }
  }
  __syncthreads();

  // ---- phased in-place normalize sweep: e-bf16 (EB) -> f32 weights (WB)
  // w-row j destroys e-rows 2j-32, 2j-31
  const int pr0[5] = {0, 16, 24, 28, 30};
  const int pr1[5] = {16, 24, 28, 30, 32};
  float* WBf = (float*)WB;
#pragma unroll 1
  for (int ph = 0; ph < 5; ++ph) {
    for (int r = pr0[ph] + w; r < pr1[ph]; r += 8) {
      const float rinv = 1.0f / lsum_l[r];
      const short* erow = (r >= 30) ? (const short*)(kbuf + (size_t)(r - 30) * 8192)
                                    : (const short*)(EB + (size_t)r * 8192);
      float* wrow = WBf + (size_t)r * 4096;
      for (int c = lane * 8; c < 4096; c += 512) {
        short8 ev = *(const short8*)(erow + c);
        f32x4 o0, o1;
#pragma unroll
        for (int j = 0; j < 4; ++j) o0[j] = bf2f(ev[j]) * rinv;
#pragma unroll
        for (int j = 0; j < 4; ++j) o1[j] = bf2f(ev[4 + j]) * rinv;
        *(f32x4*)(wrow + c) = o0;
        *(f32x4*)(wrow + c + 4) = o1;
      }
    }
    __syncthreads();
  }
}

// ---------------------------------------------------------------- launch
extern "C" void kernel_launch(void* const* d_in, const int* in_sizes, int n_in,
                              void* d_out, int out_size, void* d_ws, size_t ws_size,
                              hipStream_t stream) {
  const float* x  = (const float*)d_in[0];
  const float* wq = (const float*)d_in[1];
  const float* wk = (const float*)d_in[2];
  const float* wv = (const float*)d_in[3];

  float* out = (float*)d_out;                    // [B][S][D]
  float* wts = out + (size_t)B_ * S_ * D_;       // [B][S][S]

  // workspace layout (~63.5 MB)
  short* xh = (short*)d_ws;
  short* xl = xh + NQ;
  short* qh = xl + NQ;
  short* ql = qh + NQ;
  short* kh = ql + NQ;
  short* kl = kh + NQ;
  short* vt = kl + NQ;                 // [B][D][S] bf16
  short* wh = vt + NQ;                 // [3][D][D] bf16
  short* wl = wh + 3 * NW;
  float* ctab = (float*)(wl + 3 * NW); // [S][128] (cos,sin) fp32

  k0_split<<<dim3((NQ + 3 * NW + NTAB) / 256), 256, 0, stream>>>(
      x, wq, wk, wv, xh, xl, wh, wl, ctab);
  k1_proj<<<dim3(B_ * S_ / 64, 3), 256, 0, stream>>>(
      xh, xl, wh, wl, ctab, qh, ql, kh, kl, vt);
  k2_fused<<<dim3(512), 512, 0, stream>>>(
      qh, ql, kh, kl, vt, wts, out);
}

// Round 9
// 446.377 us; speedup vs baseline: 1.4699x; 1.4699x over previous
//
#include <hip/hip_runtime.h>
#include <hip/hip_bf16.h>
#include <stdint.h>

// RoPEDemoAttention on MI355X (gfx950)
// B=4, S=4096, D=256. fp32 in/out.
// K0: split fp32 -> bf16 hi/lo + RoPE cos/sin table.
// K1: Q/K/V projections via 3-pass split-bf16 MFMA + RoPE.
// K2 (R9): 512 blocks x 256 threads (4 waves) x 32 q-rows, 32-key tiles
//   (hi+lo staged, dbuf). LDS ~68K -> TWO INDEPENDENT blocks per CU
//   (R8 missed co-residency by ~1KB: usable LDS/CU ~149K; R5 proved
//   74240x2 co-resides). Same 1-barrier pipelined skeleton:
//     stage(kt+1) -> ecopy+PV(kt-1) -> scores(kt) -> exp -> barrier
//   then rowsums, normalized out, 5-phase in-place e->weights sweep.
//   Reductions + e-rows-30/31 scratch aliased into kbuf (dead after loop).

#define B_ 4
#define S_ 4096
#define D_ 256
#define NQ 4194304   // B_*S_*D_
#define NW 65536     // D_*D_
#define NTAB 524288  // S_*128 table entries (cos,sin pairs)

typedef __attribute__((ext_vector_type(4))) float f32x4;
typedef __attribute__((ext_vector_type(8))) short short8;
typedef __attribute__((ext_vector_type(4))) short short4v;
typedef __attribute__((ext_vector_type(4))) unsigned uint32x4;

__device__ __forceinline__ short f2bf(float f) {
  unsigned u = __builtin_bit_cast(unsigned, f);
  u += 0x7fffu + ((u >> 16) & 1u);   // RNE
  return (short)(u >> 16);
}
__device__ __forceinline__ float bf2f(short h) {
  unsigned u = ((unsigned)(unsigned short)h) << 16;
  return __builtin_bit_cast(float, u);
}

__device__ __forceinline__ void gload16(const void* g, void* l) {
  __builtin_amdgcn_global_load_lds(
      (const __attribute__((address_space(1))) unsigned*)g,
      (__attribute__((address_space(3))) unsigned*)l, 16, 0, 0);
}

// ------------------------------------------------ K0: split + RoPE table
__global__ __launch_bounds__(256) void k0_split(
    const float* __restrict__ x, const float* __restrict__ wq,
    const float* __restrict__ wk, const float* __restrict__ wv,
    short* __restrict__ xh, short* __restrict__ xl,
    short* __restrict__ wh, short* __restrict__ wl,
    float* __restrict__ ctab) {
  int idx = blockIdx.x * 256 + threadIdx.x;  // grid = NQ + 3*NW + NTAB
  if (idx < NQ) {
    float v = x[idx];
    short hi = f2bf(v);
    xh[idx] = hi;
    xl[idx] = f2bf(v - bf2f(hi));
  } else if (idx < NQ + 3 * NW) {
    int r = idx - NQ;
    int m = r >> 16;
    int e = r & (NW - 1);
    const float* w = (m == 0) ? wq : (m == 1) ? wk : wv;
    float v = w[e];
    short hi = f2bf(v);
    wh[r] = hi;
    wl[r] = f2bf(v - bf2f(hi));
  } else {
    int t = idx - NQ - 3 * NW;          // t < NTAB
    int s = t >> 7, j = t & 127;
    float invf = __expf(-0.07195578415606394f * (float)j); // 10000^(-j/128)
    float sn, cs;
    sincosf((float)s * invf, &sn, &cs);
    ctab[2 * t] = cs;
    ctab[2 * t + 1] = sn;
  }
}

// ------------------------------------------------------- K1: proj + RoPE
__global__ __launch_bounds__(256) void k1_proj(
    const short* __restrict__ xh, const short* __restrict__ xl,
    const short* __restrict__ wh, const short* __restrict__ wl,
    const float* __restrict__ ctab,
    short* __restrict__ qh, short* __restrict__ ql,
    short* __restrict__ kh, short* __restrict__ kl,
    short* __restrict__ vt) {
  const int m = blockIdx.y;                 // 0=q 1=k 2=v
  const int b = blockIdx.x >> 6;
  const int sbase = (blockIdx.x & 63) << 6; // 64-row tile
  const int tid = threadIdx.x;
  const int w = tid >> 6;
  const int lane = tid & 63;
  const int lr = lane & 15;
  const int g = lane >> 4;

  const int srow = sbase + w * 16 + lr;     // A-frag row
  const short* xhp = xh + ((size_t)(b * S_ + srow)) * D_;
  const short* xlp = xl + ((size_t)(b * S_ + srow)) * D_;
  const short* whm = wh + m * NW;
  const short* wlm = wl + m * NW;

  f32x4 acc[16];
#pragma unroll
  for (int i = 0; i < 16; ++i) acc[i] = (f32x4)0.f;

#pragma unroll
  for (int dc = 0; dc < 8; ++dc) {
    const int d = dc * 32 + g * 8;
    short8 ah = *(const short8*)(xhp + d);
    short8 al = *(const short8*)(xlp + d);
#pragma unroll
    for (int ct = 0; ct < 16; ++ct) {
      const int e = ct * 16 + lr;
      short8 bh = *(const short8*)(whm + e * D_ + d);
      short8 bl = *(const short8*)(wlm + e * D_ + d);
      acc[ct] = __builtin_amdgcn_mfma_f32_16x16x32_bf16(ah, bh, acc[ct], 0, 0, 0);
      acc[ct] = __builtin_amdgcn_mfma_f32_16x16x32_bf16(ah, bl, acc[ct], 0, 0, 0);
      acc[ct] = __builtin_amdgcn_mfma_f32_16x16x32_bf16(al, bh, acc[ct], 0, 0, 0);
    }
  }

  const int s0 = sbase + w * 16 + g * 4;    // C/D row base
  if (m == 2) {
#pragma unroll
    for (int ct = 0; ct < 16; ++ct) {
      const int e = ct * 16 + lr;
      short4v pk;
#pragma unroll
      for (int r = 0; r < 4; ++r) pk[r] = f2bf(acc[ct][r]);
      *(short4v*)(vt + ((size_t)(b * D_ + e)) * S_ + s0) = pk;
    }
  } else {
    short* oh = (m == 0) ? qh : kh;
    short* ol = (m == 0) ? ql : kl;
#pragma unroll
    for (int ct = 0; ct < 16; ++ct) {
      const int e = ct * 16 + lr;
      const float sgn = (e & 1) ? 1.0f : -1.0f;  // rotate_half sign
#pragma unroll
      for (int r = 0; r < 4; ++r) {
        float v = acc[ct][r];
        float p = __shfl_xor(v, 1, 64);          // partner e^1, same s
        const float2 cs2 = *(const float2*)(ctab + ((size_t)((s0 + r) << 7) + (e & 127)) * 2);
        float q2 = v * cs2.x + sgn * p * cs2.y;
        short hi = f2bf(q2);
        size_t off = ((size_t)(b * S_ + s0 + r)) * D_ + e;
        oh[off] = hi;
        ol[off] = f2bf(q2 - bf2f(hi));
      }
    }
  }
}

// ------ K2 fused: 32-q / 4-wave blocks, 2 independent blocks per CU
__global__ __launch_bounds__(256, 2) void k2_fused(
    const short* __restrict__ qh, const short* __restrict__ ql,
    const short* __restrict__ kh, const short* __restrict__ kl,
    const short* __restrict__ vt,
    float* __restrict__ wts, float* __restrict__ out) {
  __shared__ __align__(16) char kbuf[65536];    // [2][Khi 16K | Klo 16K]
  __shared__ __align__(16) char etile[2][2048]; // e bf16 [32][32], swizzled
  // aliased after the K-loop (kbuf is dead then):
  float* partA = (float*)(kbuf + 49152);   // [2][32]
  float* lsumA = (float*)(kbuf + 50176);   // [32]

  const int bid = blockIdx.x;        // 512 blocks
  // XCD-pinning, co-resident-adjacent bijective swizzle (R8, verified)
  const int swz = (bid & 7) * 64 + ((bid >> 3) & 31) * 2 + (bid >> 8);
  const int b = swz >> 7;            // batch
  const int qbase = (swz & 127) << 5;
  const int tid = threadIdx.x;       // 256
  const int w = tid >> 6;            // 4 waves
  const int lane = tid & 63;
  const int lr = lane & 15;
  const int g = lane >> 4;
  const int qg = w & 1;              // scores: which 16 q-rows
  const int kg = w >> 1;             // scores: which 16 keys of 32-key tile

  // Q hi/lo fragments (B-operand): 16 q-rows/wave -> 64 VGPR, resident
  short8 qfh[8], qfl[8];
  {
    const int qrow = qbase + qg * 16 + lr;
    const short* ph = qh + ((size_t)(b * S_ + qrow)) * D_;
    const short* pl = ql + ((size_t)(b * S_ + qrow)) * D_;
#pragma unroll
    for (int dc = 0; dc < 8; ++dc) {
      qfh[dc] = *(const short8*)(ph + dc * 32 + g * 8);
      qfl[dc] = *(const short8*)(pl + dc * 32 + g * 8);
    }
  }

  f32x4 acc = (f32x4)0.f;            // 16q x 16k per wave
  f32x4 accv[2][4];                  // PV: 32q x 64d per wave
#pragma unroll
  for (int qs = 0; qs < 2; ++qs)
#pragma unroll
    for (int dt = 0; dt < 4; ++dt) accv[qs][dt] = (f32x4)0.f;
  float rs = 0.f;

  const char* khb = (const char*)(kh + (size_t)b * S_ * D_);
  const char* klb = (const char*)(kl + (size_t)b * S_ * D_);
  const short* vtb = vt + (size_t)b * D_ * S_;
  const int swx = (lane & 7) << 4;   // K-LDS swizzle: (key&7)<<4

  // block's weights region (512 KiB); e-bf16 scratch in its top half
  char* WB = (char*)(wts + ((size_t)(b * S_ + qbase)) * S_);
  char* EB = WB + 262144;            // [32 rows][8192 B]

  auto STAGE = [&](int kt, char* dst) {
#pragma unroll
    for (int i = 0; i < 4; ++i) {
      const int p = i * 4096 + tid * 16;
      const int xo = p ^ (((p >> 9) & 7) << 4);
      gload16(khb + (size_t)kt * 16384 + xo, dst + p);
      gload16(klb + (size_t)kt * 16384 + xo, dst + 16384 + p);
    }
  };

  // prologue: stage tile 0 into kbuf[0]
  STAGE(0, kbuf);
  __syncthreads();

  for (int kt = 0; kt < 128; ++kt) {
    const int cur = kt & 1;
    const char* kb = kbuf + cur * 32768;

    // 1. stage next 32-key tile into the other buffer
    if (kt < 127) STAGE(kt + 1, kbuf + (cur ^ 1) * 32768);

    // 2. e-copy + PV of the PREVIOUS tile (etile[cur^1])
    if (kt > 0) {
      const char* et = etile[cur ^ 1];
      {
        const int p = tid * 8;             // 256 thr * 8B = 2 KB
        const int row = p >> 6, cb = p & 63;
        uint2 v = *(const uint2*)(et + (p ^ ((row & 3) << 4)));
        *(uint2*)(EB + (size_t)row * 8192 + (kt - 1) * 64 + cb) = v;
      }
      __builtin_amdgcn_s_setprio(1);
      short8 ea0 = *(const short8*)(et + ((lr * 64 + g * 16) ^ ((lr & 3) << 4)));
      short8 ea1 = *(const short8*)(et + (((16 + lr) * 64 + g * 16) ^ ((lr & 3) << 4)));
#pragma unroll
      for (int dt = 0; dt < 4; ++dt) {
        const int d = w * 64 + dt * 16 + lr;
        short8 vb = *(const short8*)(vtb + (size_t)d * S_ + (kt - 1) * 32 + g * 8);
        accv[0][dt] = __builtin_amdgcn_mfma_f32_16x16x32_bf16(ea0, vb, accv[0][dt], 0, 0, 0);
        accv[1][dt] = __builtin_amdgcn_mfma_f32_16x16x32_bf16(ea1, vb, accv[1][dt], 0, 0, 0);
      }
      __builtin_amdgcn_s_setprio(0);
    }

    // 3. scores: 3-pass split bf16, S^T = K * Q^T (16q x 16k per wave)
    __builtin_amdgcn_s_setprio(1);
#pragma unroll
    for (int dc = 0; dc < 8; ++dc) {
      const int row = kg * 16 + lr;
      const int x = (row * 512 + dc * 64 + g * 16) ^ swx;
      short8 afh = *(const short8*)(kb + x);
      short8 afl = *(const short8*)(kb + 16384 + x);
      acc = __builtin_amdgcn_mfma_f32_16x16x32_bf16(afh, qfh[dc], acc, 0, 0, 0);
      acc = __builtin_amdgcn_mfma_f32_16x16x32_bf16(afh, qfl[dc], acc, 0, 0, 0);
      acc = __builtin_amdgcn_mfma_f32_16x16x32_bf16(afl, qfh[dc], acc, 0, 0, 0);
    }
    __builtin_amdgcn_s_setprio(0);

    // 4. e = exp(s/16) -> etile[cur] (bf16, swizzled) + rowsum
    {
      f32x4 e;
#pragma unroll
      for (int r = 0; r < 4; ++r) e[r] = __expf(acc[r] * 0.0625f);
      rs += e[0] + e[1] + e[2] + e[3];
      unsigned lo = (unsigned)(unsigned short)f2bf(e[0]) |
                    ((unsigned)(unsigned short)f2bf(e[1]) << 16);
      unsigned hi2 = (unsigned)(unsigned short)f2bf(e[2]) |
                     ((unsigned)(unsigned short)f2bf(e[3]) << 16);
      const int row = qg * 16 + lr;
      const int colb = (kg * 16 + g * 4) * 2;
      const int ad = (row * 64 + colb) ^ ((row & 3) << 4);
      *(uint2*)(etile[cur] + ad) = make_uint2(lo, hi2);
      acc = (f32x4)0.f;
    }
    __syncthreads();   // ONE barrier per tile
  }

  // ---- tail: e-copy + PV of tile 127 (etile[1])
  {
    const char* et = etile[1];
    {
      const int p = tid * 8;
      const int row = p >> 6, cb = p & 63;
      uint2 v = *(const uint2*)(et + (p ^ ((row & 3) << 4)));
      *(uint2*)(EB + (size_t)row * 8192 + 127 * 64 + cb) = v;
    }
    short8 ea0 = *(const short8*)(et + ((lr * 64 + g * 16) ^ ((lr & 3) << 4)));
    short8 ea1 = *(const short8*)(et + (((16 + lr) * 64 + g * 16) ^ ((lr & 3) << 4)));
#pragma unroll
    for (int dt = 0; dt < 4; ++dt) {
      const int d = w * 64 + dt * 16 + lr;
      short8 vb = *(const short8*)(vtb + (size_t)d * S_ + 127 * 32 + g * 8);
      accv[0][dt] = __builtin_amdgcn_mfma_f32_16x16x32_bf16(ea0, vb, accv[0][dt], 0, 0, 0);
      accv[1][dt] = __builtin_amdgcn_mfma_f32_16x16x32_bf16(ea1, vb, accv[1][dt], 0, 0, 0);
    }
  }

  // ---- rowsums -> lsumA (aliased in kbuf; kbuf K-data is dead now)
  rs += __shfl_xor(rs, 16, 64);
  rs += __shfl_xor(rs, 32, 64);
  if (lane < 16) partA[kg * 32 + qg * 16 + lane] = rs;
  __syncthreads();   // drains EB stores (vmcnt) + partA visible
  if (tid < 32) lsumA[tid] = partA[tid] + partA[32 + tid];
  __syncthreads();

  // ---- copy e rows 30,31 into kbuf (their EB copies overwritten last)
#pragma unroll
  for (int i = 0; i < 4; ++i) {
    const int p = i * 4096 + tid * 16;
    *(uint32x4*)(kbuf + p) = *(const uint32x4*)(EB + (size_t)30 * 8192 + p);
  }

  // ---- normalized output write
  {
    float* ob = out + (size_t)b * S_ * D_;
    float rv[2][4];
#pragma unroll
    for (int qs = 0; qs < 2; ++qs)
#pragma unroll
      for (int r = 0; r < 4; ++r)
        rv[qs][r] = 1.0f / lsumA[qs * 16 + g * 4 + r];
#pragma unroll
    for (int qs = 0; qs < 2; ++qs)
#pragma unroll
      for (int dt = 0; dt < 4; ++dt)
#pragma unroll
        for (int r = 0; r < 4; ++r) {
          const int q = qbase + qs * 16 + g * 4 + r;
          ob[(size_t)q * D_ + w * 64 + dt * 16 + lr] = accv[qs][dt][r] * rv[qs][r];
        }
  }
  __syncthreads();

  // ---- phased in-place normalize sweep: e-bf16 (EB) -> f32 weights (WB)
  // w-row j destroys e-rows 2j-32, 2j-31 (j>=16)
  const int pr0[5] = {0, 16, 24, 28, 30};
  const int pr1[5] = {16, 24, 28, 30, 32};
  float* WBf = (float*)WB;
#pragma unroll 1
  for (int ph = 0; ph < 5; ++ph) {
    for (int r = pr0[ph] + w; r < pr1[ph]; r += 4) {
      const float rinv = 1.0f / lsumA[r];
      const short* erow = (r >= 30) ? (const short*)(kbuf + (size_t)(r - 30) * 8192)
                                    : (const short*)(EB + (size_t)r * 8192);
      float* wrow = WBf + (size_t)r * 4096;
      for (int c = lane * 8; c < 4096; c += 512) {
        short8 ev = *(const short8*)(erow + c);
        f32x4 o0, o1;
#pragma unroll
        for (int j = 0; j < 4; ++j) o0[j] = bf2f(ev[j]) * rinv;
#pragma unroll
        for (int j = 0; j < 4; ++j) o1[j] = bf2f(ev[4 + j]) * rinv;
        *(f32x4*)(wrow + c) = o0;
        *(f32x4*)(wrow + c + 4) = o1;
      }
    }
    __syncthreads();
  }
}

// ---------------------------------------------------------------- launch
extern "C" void kernel_launch(void* const* d_in, const int* in_sizes, int n_in,
                              void* d_out, int out_size, void* d_ws, size_t ws_size,
                              hipStream_t stream) {
  const float* x  = (const float*)d_in[0];
  const float* wq = (const float*)d_in[1];
  const float* wk = (const float*)d_in[2];
  const float* wv = (const float*)d_in[3];

  float* out = (float*)d_out;                    // [B][S][D]
  float* wts = out + (size_t)B_ * S_ * D_;       // [B][S][S]

  // workspace layout (~63.5 MB)
  short* xh = (short*)d_ws;
  short* xl = xh + NQ;
  short* qh = xl + NQ;
  short* ql = qh + NQ;
  short* kh = ql + NQ;
  short* kl = kh + NQ;
  short* vt = kl + NQ;                 // [B][D][S] bf16
  short* wh = vt + NQ;                 // [3][D][D] bf16
  short* wl = wh + 3 * NW;
  float* ctab = (float*)(wl + 3 * NW); // [S][128] (cos,sin) fp32

  k0_split<<<dim3((NQ + 3 * NW + NTAB) / 256), 256, 0, stream>>>(
      x, wq, wk, wv, xh, xl, wh, wl, ctab);
  k1_proj<<<dim3(B_ * S_ / 64, 3), 256, 0, stream>>>(
      xh, xl, wh, wl, ctab, qh, ql, kh, kl, vt);
  k2_fused<<<dim3(512), 256, 0, stream>>>(
      qh, ql, kh, kl, vt, wts, out);
}